// Round 15
// baseline (178.801 us; speedup 1.0000x reference)
//
#include <hip/hip_runtime.h>
#include <math.h>

#define VOCAB 1024
#define ED 64
#define NROWS 65536            // 64*32*32 flattened rows
#define NELEM 4194304          // 64*64*32*32
#define MARGIN 2.0e-4f         // validated R3/R4 (passed, absmax 0)

typedef __attribute__((ext_vector_type(8))) short short8;
typedef __attribute__((ext_vector_type(4))) float f32x4;

__device__ __forceinline__ unsigned f2bf(float f) {
    unsigned u = __float_as_uint(f);
    u += 0x7fff + ((u >> 16) & 1);   // RNE to bf16
    return u >> 16;
}

// pack (distance, code) into a sortable u64 key: min(key) == lex-min (d, c)
__device__ __forceinline__ unsigned long long packkey(float d, int c) {
    unsigned f = __float_as_uint(d);
    unsigned sd = (f & 0x80000000u) ? ~f : (f | 0x80000000u);
    return ((unsigned long long)sd << 32) | (unsigned)c;
}

// ws layout:
//   [0,      4096)   float e2f[1024]     fl32(fp64 ||e||^2)  (R2-proven)
//   [4096,   8192)   unsigned hist[1024]
//   [8192,   139264) uint4 FB[8192]      bf16 MFMA-B fragments (128 KB)
//   [139264, 147456) double lossp[1024]  per-main-block loss partials
//   [147456, 147460) unsigned donecnt    last-block-finalize counter
//
// FB fragment layout (identical bits to round-0 stage_chunk):
//   entry i: n=i&15, q=(i>>4)&3, kh=(i>>6)&1, T=i>>7
//   holds bf16x8 of emb[T*16+n][kh*32+q*8 .. +8)
//   scan reads bf[kh] = ((short8*)FB)[T*128 + kh*64 + lane], lane=q*16+n_lo

// ---------------- prep: e2f + bf16 fragment table + hist/donecnt zeroing ----------------
__global__ void vq_prep(const float* __restrict__ emb, float* __restrict__ e2f,
                        uint4* __restrict__ FB, unsigned* __restrict__ hist,
                        unsigned* __restrict__ donecnt) {
    const int tid = blockIdx.x * 256 + threadIdx.x;   // 0..2047
    if (tid < 1024) hist[tid] = 0u;
    if (tid == 0) *donecnt = 0u;

    if (tid < VOCAB) {
        const float4* src = (const float4*)(emb + tid * ED);
        double s = 0.0;
        #pragma unroll
        for (int g = 0; g < 16; ++g) {
            float4 f = src[g];
            s = fma((double)f.x, (double)f.x, s);
            s = fma((double)f.y, (double)f.y, s);
            s = fma((double)f.z, (double)f.z, s);
            s = fma((double)f.w, (double)f.w, s);
        }
        e2f[tid] = (float)s;
    }
    #pragma unroll
    for (int e = 0; e < 4; ++e) {
        const int i = e * 2048 + tid;                 // 0..8191
        const int n = i & 15, q = (i >> 4) & 3, kh = (i >> 6) & 1, T = i >> 7;
        const int code = T * 16 + n;
        const int k0 = kh * 32 + q * 8;
        const float4* sp = (const float4*)(emb + code * 64 + k0);
        float4 f0 = sp[0], f1 = sp[1];
        uint4 pk;
        pk.x = f2bf(f0.x) | (f2bf(f0.y) << 16);
        pk.y = f2bf(f0.z) | (f2bf(f0.w) << 16);
        pk.z = f2bf(f1.x) | (f2bf(f1.y) << 16);
        pk.w = f2bf(f1.z) | (f2bf(f1.w) << 16);
        FB[i] = pk;
    }
}

// ---------------- main: R12 scan(top-3) + flag + pair/full rescue + epilogue
// (byte-identical hot code to R12, 86us, passed absmax 0) + R14-validated
// last-block finalize fusion (release fence + device atomic + acquire fence). ----------
__global__ __launch_bounds__(256, 2)
void vq_main(const float* __restrict__ z, const float* __restrict__ emb,
             const float* __restrict__ e2f, const uint4* __restrict__ FB,
             float* __restrict__ out, double* __restrict__ lossp,
             unsigned* __restrict__ hist, unsigned* __restrict__ donecnt) {
    __shared__ float e2s[1024];
    __shared__ float rowb1[64], rowb2[64], rowb3[64];
    __shared__ int   rowi1[64], rowi2[64], rowfi[64];
    __shared__ float zs[64 * 64];                 // 16 KB: flagged rows' z
    __shared__ float znsh[64];
    __shared__ int   flrows[64], frows2[64];
    __shared__ int   flcs, nfulls;
    __shared__ double wls[4];
    __shared__ unsigned lastflag;
    __shared__ double red[256], red2[256];        // last-block finalize

    const int t = threadIdx.x;
    const int w = t >> 6, lane = t & 63;
    const int q = lane >> 4, n_lo = lane & 15;
    const int bk = blockIdx.x;           // 1024 blocks, 64 rows each
    const int n0 = bk * 64;
    const int b  = n0 >> 10;
    const int sb = n0 & 1023;

    #pragma unroll
    for (int i = 0; i < 4; ++i) e2s[i * 256 + t] = e2f[i * 256 + t];

    // A fragments: bf16(-2 z) for this wave's 16 rows (R2-validated, bit-identical)
    short8 af[2];
    {
        const int s = sb + w * 16 + n_lo;
        const float* zp = z + (size_t)b * 65536 + s;
        #pragma unroll
        for (int kh = 0; kh < 2; ++kh) {
            short8 fr;
            #pragma unroll
            for (int j = 0; j < 8; ++j) {
                int d = kh * 32 + q * 8 + j;
                fr[j] = (short)f2bf(-2.0f * zp[d * 1024]);
            }
            af[kh] = fr;
        }
    }

    float b1[4], b2[4], b3[4]; int i1[4], i2[4];
    #pragma unroll
    for (int sl = 0; sl < 4; ++sl) {
        b1[sl] = 3.4e38f; b2[sl] = 3.4e38f; b3[sl] = 3.4e38f;
        i1[sl] = 0; i2[sl] = 0;
    }

    __syncthreads();                     // e2s ready

    // ---- MFMA scan: 64 tiles, B-fragments straight from global (R12 loop, UNCHANGED) ----
    const short8* FBs = (const short8*)FB;
    #pragma unroll 4
    for (int T = 0; T < 64; ++T) {
        short8 bf0 = FBs[T * 128 + lane];          // kh=0
        short8 bf1 = FBs[T * 128 + 64 + lane];     // kh=1
        const int cb = T * 16 + n_lo;
        const float e2 = e2s[cb];
        f32x4 a; a[0] = e2; a[1] = e2; a[2] = e2; a[3] = e2;
        a = __builtin_amdgcn_mfma_f32_16x16x32_bf16(af[0], bf0, a, 0, 0, 0);
        a = __builtin_amdgcn_mfma_f32_16x16x32_bf16(af[1], bf1, a, 0, 0, 0);
        #pragma unroll
        for (int reg = 0; reg < 4; ++reg) {
            float s0 = a[reg];
            // order matters: b3 uses OLD b2; i2 uses OLD b1/b2/i1 (sequential semantics)
            b3[reg] = __builtin_amdgcn_fmed3f(s0, b2[reg], b3[reg]);
            bool lt2 = s0 < b2[reg];
            bool lt  = s0 < b1[reg];
            i2[reg] = lt2 ? (lt ? i1[reg] : cb) : i2[reg];
            b2[reg] = __builtin_amdgcn_fmed3f(s0, b1[reg], b2[reg]);
            i1[reg] = lt ? cb : i1[reg];
            b1[reg] = lt ? s0 : b1[reg];
        }
    }

    // merge across the 16 code-lanes of each quad (R12-validated network)
    #pragma unroll
    for (int m = 1; m < 16; m <<= 1) {
        #pragma unroll
        for (int sl = 0; sl < 4; ++sl) {
            float oa1 = __shfl_xor(b1[sl], m, 64);
            float oa2 = __shfl_xor(b2[sl], m, 64);
            float oa3 = __shfl_xor(b3[sl], m, 64);
            int   oj1 = __shfl_xor(i1[sl], m, 64);
            int   oj2 = __shfl_xor(i2[sl], m, 64);
            bool take = (oa1 < b1[sl]) || (oa1 == b1[sl] && oj1 < i1[sl]);
            float w1  = take ? oa1 : b1[sl];  int ni1 = take ? oj1 : i1[sl];
            float l1v = take ? b1[sl] : oa1;  int il1 = take ? i1[sl] : oj1;
            float wt2 = take ? oa2 : b2[sl];  int iw2 = take ? oj2 : i2[sl];
            float wt3 = take ? oa3 : b3[sl];
            float lt2v = take ? b2[sl] : oa2;
            bool t2 = wt2 < l1v;
            float nb2 = t2 ? wt2 : l1v;       int ni2 = t2 ? iw2 : il1;
            float nb3 = fminf(fmaxf(l1v, wt2), fminf(wt3, lt2v));
            b1[sl] = w1;  i1[sl] = ni1;
            b2[sl] = nb2; i2[sl] = ni2;
            b3[sl] = nb3;
        }
    }
    if (n_lo == 0) {
        #pragma unroll
        for (int reg = 0; reg < 4; ++reg) {
            int row = w * 16 + q * 4 + reg;
            rowb1[row] = b1[reg];
            rowb2[row] = b2[reg];
            rowb3[row] = b3[reg];
            rowi1[row] = i1[reg];
            rowi2[row] = i2[reg];
        }
    }
    __syncthreads();

    // ---- flag rows (wave 0): pair (b2 within margin) / full (b3 within margin) ----
    if (t < 64) {
        const float thr = rowb1[t] + MARGIN;
        const bool pf = rowb2[t] < thr;
        const bool ff = rowb3[t] < thr;      // ff implies pf (b3 >= b2)
        unsigned long long pm = __ballot(pf);
        if (t == 0) flcs = __popcll(pm);
        if (pf) {
            const int rank = __popcll(pm & ((1ULL << t) - 1ULL));
            flrows[rank] = t | (ff ? 256 : 0);
            rowfi[t] = rank;
        }
        unsigned long long fm = __ballot(ff);
        if (t == 0) nfulls = __popcll(fm);
        if (ff) {
            const int rank = __popcll(fm & ((1ULL << t) - 1ULL));
            frows2[rank] = t;
        }
    }
    __syncthreads();
    const int flc = flcs;                // block-uniform
    const int nfull = nfulls;

    if (flc > 0) {
        // stage z rows: 4 threads/row, 16 dims each (L2/L3-hot scattered reads)
        {
            const int fi = t >> 2, d0 = (t & 3) * 16;
            if (fi < flc) {
                const int r = flrows[fi] & 255;
                const float* zp = z + (size_t)b * 65536 + (size_t)d0 * 1024 + (sb + r);
                #pragma unroll
                for (int k = 0; k < 16; ++k)
                    zs[fi * 64 + d0 + k] = zp[(size_t)k * 1024];
            }
        }
        __syncthreads();
        // zn per flagged row: fl32(fp64 sequential ||z||^2) (R2-proven chain)
        if (t < flc) {
            const float* zp = zs + t * 64;
            double a = 0.0;
            for (int k = 0; k < 64; ++k) { const double v = (double)zp[k]; a = fma(v, v, a); }
            znsh[t] = (float)a;
        }
        __syncthreads();

        // ---- pair-rescue: thread per flagged (non-full) row; exact chain on {i1,i2} ----
        if (t < flc) {
            const int ent = flrows[t];
            if (!(ent & 256)) {
                const int r = ent & 255;
                const float zn = znsh[t];
                const int c1 = rowi1[r], c2 = rowi2[r];
                const float* zp = zs + t * 64;
                const float4* e1p = (const float4*)(emb + (size_t)c1 * 64);
                const float4* e2p = (const float4*)(emb + (size_t)c2 * 64);
                float m1 = 0.f, m2 = 0.f;
                #pragma unroll
                for (int k4 = 0; k4 < 16; ++k4) {    // strict sequential k (R2-exact)
                    const float4 zz = *(const float4*)(zp + k4 * 4);
                    const float4 ea = e1p[k4], eb = e2p[k4];
                    m1 = fmaf(zz.x, ea.x, m1); m1 = fmaf(zz.y, ea.y, m1);
                    m1 = fmaf(zz.z, ea.z, m1); m1 = fmaf(zz.w, ea.w, m1);
                    m2 = fmaf(zz.x, eb.x, m2); m2 = fmaf(zz.y, eb.y, m2);
                    m2 = fmaf(zz.z, eb.z, m2); m2 = fmaf(zz.w, eb.w, m2);
                }
                const float t1 = zn + e2s[c1];
                const float t2v = zn + e2s[c2];
                const float d1 = t1 - 2.0f * m1;
                const float d2 = t2v - 2.0f * m2;
                // lex-min (d, c): first-occurrence semantics
                const int cw = (d2 < d1 || (d2 == d1 && c2 < c1)) ? c2 : c1;
                rowi1[r] = cw;
            }
        }

        // ---- full-rescue: one wave per b3-flagged row (rare); lane owns 16 codes ----
        for (int fj = w; fj < nfull; fj += 4) {
            const int r = frows2[fj];
            const int fi = rowfi[r];
            const float zn = znsh[fi];
            const float4* zz4 = (const float4*)(zs + fi * 64);
            unsigned long long best = ~0ULL;
            #pragma unroll 1
            for (int j = 0; j < 16; ++j) {
                const int c = j * 64 + lane;
                const float4* ep4 = (const float4*)(emb + (size_t)c * 64);
                float m = 0.f;
                #pragma unroll
                for (int k4 = 0; k4 < 16; ++k4) {    // strict sequential k (R2-exact)
                    const float4 e4v = ep4[k4];
                    const float4 zz = zz4[k4];
                    m = fmaf(zz.x, e4v.x, m); m = fmaf(zz.y, e4v.y, m);
                    m = fmaf(zz.z, e4v.z, m); m = fmaf(zz.w, e4v.w, m);
                }
                const float tt = zn + e2s[c];
                const float d = tt - 2.0f * m;
                const unsigned long long kk = packkey(d, c);
                if (kk < best) best = kk;
            }
            #pragma unroll
            for (int mo = 32; mo > 0; mo >>= 1) {
                unsigned long long o = __shfl_xor(best, mo, 64);
                if (o < best) best = o;
            }
            if (lane == 0) rowi1[r] = (int)(unsigned)(best & 0xffffffffu);
        }
        __syncthreads();
    }

    // ---- index + hist with FINAL codes ----
    if (t < 64) {
        const int code = rowi1[t];
        out[NELEM + n0 + t] = (float)code;
        atomicAdd(&hist[code], 1u);      // distributed addresses
    }

    // ---- epilogue: COALESCED z_q_st + loss for ALL rows with final codes ----
    // (R2-validated mapping: thread (w,lane): row=lane, dims [w*16, w*16+16))
    {
        const int r = lane;
        const int code2 = rowi1[r];
        const int scol = sb + r;
        double lsum = 0.0;
        #pragma unroll
        for (int i = 0; i < 4; ++i) {
            const int d4 = w * 4 + i;
            float4 e4 = *(const float4*)(emb + code2 * 64 + d4 * 4);  // gather, L1/L2-hot
            float es[4] = {e4.x, e4.y, e4.z, e4.w};
            #pragma unroll
            for (int j = 0; j < 4; ++j) {
                int d = d4 * 4 + j;
                size_t off = (size_t)b * 65536 + (size_t)d * 1024 + scol;
                float zv = z[off];                 // coalesced 256B
                out[off] = zv + (es[j] - zv);      // coalesced 256B
                double df = (double)es[j] - (double)zv;
                lsum = fma(df, df, lsum);
            }
        }
        #pragma unroll
        for (int off = 32; off > 0; off >>= 1)
            lsum += __shfl_down(lsum, off, 64);
        if (lane == 0) wls[w] = lsum;
    }
    __syncthreads();

    // ---- publish loss partial + last-block finalize (R14-validated pattern) ----
    if (t == 0) {
        lossp[bk] = wls[0] + wls[1] + wls[2] + wls[3];   // NO atomic
        __threadfence();                                  // release lossp store
        unsigned d = atomicAdd(donecnt, 1u);              // device-scope
        lastflag = (d == 1023u) ? 1u : 0u;
    }
    __syncthreads();
    if (lastflag) {
        __threadfence();                 // acquire: see all lossp stores + hist atomics
        double ssum = 0.0, lsum = 0.0;
        for (int i = t; i < VOCAB; i += 256) {
            double p = (double)hist[i] / (double)NROWS;
            ssum += p * log(p + 1e-10);
        }
        for (int i = t; i < 1024; i += 256) lsum += lossp[i];
        red[t] = ssum; red2[t] = lsum;
        __syncthreads();
        for (int off = 128; off > 0; off >>= 1) {
            if (t < off) { red[t] += red[t + off]; red2[t] += red2[t + off]; }
            __syncthreads();
        }
        if (t == 0) {
            double qv = red2[0] / (double)NELEM;
            out[NELEM + NROWS + 0] = (float)qv;
            out[NELEM + NROWS + 1] = (float)(qv * 0.25);
            out[NELEM + NROWS + 2] = (float)exp(-red[0]);
        }
    }
}

extern "C" void kernel_launch(void* const* d_in, const int* in_sizes, int n_in,
                              void* d_out, int out_size, void* d_ws, size_t ws_size,
                              hipStream_t stream) {
    const float* z   = (const float*)d_in[0];   // (64,64,32,32) fp32
    const float* emb = (const float*)d_in[1];   // (1024,64) fp32
    float* out = (float*)d_out;

    float*    e2f     = (float*)d_ws;
    unsigned* hist    = (unsigned*)((char*)d_ws + 4096);
    uint4*    FB      = (uint4*)((char*)d_ws + 8192);
    double*   lossp   = (double*)((char*)d_ws + 139264);
    unsigned* donecnt = (unsigned*)((char*)d_ws + 147456);

    vq_prep<<<dim3(8), dim3(256), 0, stream>>>(emb, e2f, FB, hist, donecnt);
    vq_main<<<dim3(1024), dim3(256), 0, stream>>>(z, emb, e2f, FB, out, lossp,
                                                  hist, donecnt);
}

// Round 16
// 153.930 us; speedup vs baseline: 1.1616x; 1.1616x over previous
//
#include <hip/hip_runtime.h>
#include <math.h>

#define VOCAB 1024
#define ED 64
#define NROWS 65536            // 64*32*32 flattened rows
#define NELEM 4194304          // 64*64*32*32
#define MARGIN 2.0e-4f         // validated R3/R4 (passed, absmax 0)

typedef __attribute__((ext_vector_type(8))) short short8;
typedef __attribute__((ext_vector_type(4))) float f32x4;

__device__ __forceinline__ unsigned f2bf(float f) {
    unsigned u = __float_as_uint(f);
    u += 0x7fff + ((u >> 16) & 1);   // RNE to bf16
    return u >> 16;
}

// pack (distance, code) into a sortable u64 key: min(key) == lex-min (d, c)
__device__ __forceinline__ unsigned long long packkey(float d, int c) {
    unsigned f = __float_as_uint(d);
    unsigned sd = (f & 0x80000000u) ? ~f : (f | 0x80000000u);
    return ((unsigned long long)sd << 32) | (unsigned)c;
}

// ws layout:
//   [0,      4096)   float e2f[1024]     fl32(fp64 ||e||^2)  (R2-proven)
//   [4096,   8192)   unsigned hist[1024]
//   [8192,   139264) uint4 FB[8192]      bf16 MFMA-B fragments (128 KB)
//   [139264, 147456) double lossp[1024]  per-main-block loss partials
//
// FB fragment layout (identical bits to round-0 stage_chunk):
//   entry i: n=i&15, q=(i>>4)&3, kh=(i>>6)&1, T=i>>7
//   holds bf16x8 of emb[T*16+n][kh*32+q*8 .. +8)
//   scan reads bf[kh] = ((short8*)FB)[T*128 + kh*64 + lane], lane=q*16+n_lo

// ---------------- prep: e2f + bf16 fragment table + hist zeroing ----------------
__global__ void vq_prep(const float* __restrict__ emb, float* __restrict__ e2f,
                        uint4* __restrict__ FB, unsigned* __restrict__ hist) {
    const int tid = blockIdx.x * 256 + threadIdx.x;   // 0..2047
    if (tid < 1024) hist[tid] = 0u;

    if (tid < VOCAB) {
        const float4* src = (const float4*)(emb + tid * ED);
        double s = 0.0;
        #pragma unroll
        for (int g = 0; g < 16; ++g) {
            float4 f = src[g];
            s = fma((double)f.x, (double)f.x, s);
            s = fma((double)f.y, (double)f.y, s);
            s = fma((double)f.z, (double)f.z, s);
            s = fma((double)f.w, (double)f.w, s);
        }
        e2f[tid] = (float)s;
    }
    #pragma unroll
    for (int e = 0; e < 4; ++e) {
        const int i = e * 2048 + tid;                 // 0..8191
        const int n = i & 15, q = (i >> 4) & 3, kh = (i >> 6) & 1, T = i >> 7;
        const int code = T * 16 + n;
        const int k0 = kh * 32 + q * 8;
        const float4* sp = (const float4*)(emb + code * 64 + k0);
        float4 f0 = sp[0], f1 = sp[1];
        uint4 pk;
        pk.x = f2bf(f0.x) | (f2bf(f0.y) << 16);
        pk.y = f2bf(f0.z) | (f2bf(f0.w) << 16);
        pk.z = f2bf(f1.x) | (f2bf(f1.y) << 16);
        pk.w = f2bf(f1.z) | (f2bf(f1.w) << 16);
        FB[i] = pk;
    }
}

// ---------------- main: scan(top-3) + flag + pair/full rescue + epilogue ----------------
// 1024 blocks x 64 rows. Scan = R5-validated loop + b3/i2 tracking.
// Rescue: candidates {i1,i2} exact-checked when b3 clears margin (proof: any other
// code's scan score >= b3 >= b1+MARGIN => not ref-argmin, same validated bound);
// full 1024-code exact scan only when b3 < b1+MARGIN (rare).
__global__ __launch_bounds__(256, 2)
void vq_main(const float* __restrict__ z, const float* __restrict__ emb,
             const float* __restrict__ e2f, const uint4* __restrict__ FB,
             float* __restrict__ out, double* __restrict__ lossp,
             unsigned* __restrict__ hist) {
    __shared__ float e2s[1024];
    __shared__ float rowb1[64], rowb2[64], rowb3[64];
    __shared__ int   rowi1[64], rowi2[64], rowfi[64];
    __shared__ float zs[64 * 64];                 // 16 KB: flagged rows' z
    __shared__ float znsh[64];
    __shared__ int   flrows[64], frows2[64];
    __shared__ int   flcs, nfulls;
    __shared__ double wls[4];

    const int t = threadIdx.x;
    const int w = t >> 6, lane = t & 63;
    const int q = lane >> 4, n_lo = lane & 15;
    const int bk = blockIdx.x;           // 1024 blocks, 64 rows each
    const int n0 = bk * 64;
    const int b  = n0 >> 10;
    const int sb = n0 & 1023;

    #pragma unroll
    for (int i = 0; i < 4; ++i) e2s[i * 256 + t] = e2f[i * 256 + t];

    // A fragments: bf16(-2 z) for this wave's 16 rows (R2-validated, bit-identical)
    short8 af[2];
    {
        const int s = sb + w * 16 + n_lo;
        const float* zp = z + (size_t)b * 65536 + s;
        #pragma unroll
        for (int kh = 0; kh < 2; ++kh) {
            short8 fr;
            #pragma unroll
            for (int j = 0; j < 8; ++j) {
                int d = kh * 32 + q * 8 + j;
                fr[j] = (short)f2bf(-2.0f * zp[d * 1024]);
            }
            af[kh] = fr;
        }
    }

    float b1[4], b2[4], b3[4]; int i1[4], i2[4];
    #pragma unroll
    for (int sl = 0; sl < 4; ++sl) {
        b1[sl] = 3.4e38f; b2[sl] = 3.4e38f; b3[sl] = 3.4e38f;
        i1[sl] = 0; i2[sl] = 0;
    }

    __syncthreads();                     // e2s ready

    // ---- MFMA scan: 64 tiles, B-fragments straight from global (R5 loop + top-3) ----
    const short8* FBs = (const short8*)FB;
    #pragma unroll 4
    for (int T = 0; T < 64; ++T) {
        short8 bf0 = FBs[T * 128 + lane];          // kh=0
        short8 bf1 = FBs[T * 128 + 64 + lane];     // kh=1
        const int cb = T * 16 + n_lo;
        const float e2 = e2s[cb];
        f32x4 a; a[0] = e2; a[1] = e2; a[2] = e2; a[3] = e2;
        a = __builtin_amdgcn_mfma_f32_16x16x32_bf16(af[0], bf0, a, 0, 0, 0);
        a = __builtin_amdgcn_mfma_f32_16x16x32_bf16(af[1], bf1, a, 0, 0, 0);
        #pragma unroll
        for (int reg = 0; reg < 4; ++reg) {
            float s0 = a[reg];
            // order matters: b3 uses OLD b2; i2 uses OLD b1/b2/i1 (sequential semantics)
            b3[reg] = __builtin_amdgcn_fmed3f(s0, b2[reg], b3[reg]);
            bool lt2 = s0 < b2[reg];
            bool lt  = s0 < b1[reg];
            i2[reg] = lt2 ? (lt ? i1[reg] : cb) : i2[reg];
            b2[reg] = __builtin_amdgcn_fmed3f(s0, b1[reg], b2[reg]);
            i1[reg] = lt ? cb : i1[reg];
            b1[reg] = lt ? s0 : b1[reg];
        }
    }

    // merge across the 16 code-lanes of each quad (b1/i1/b2 bit-identical to validated;
    // b3 via verified 2-sorted-triple network; i2 loose ties are safe: ambiguity => b3 tie)
    #pragma unroll
    for (int m = 1; m < 16; m <<= 1) {
        #pragma unroll
        for (int sl = 0; sl < 4; ++sl) {
            float oa1 = __shfl_xor(b1[sl], m, 64);
            float oa2 = __shfl_xor(b2[sl], m, 64);
            float oa3 = __shfl_xor(b3[sl], m, 64);
            int   oj1 = __shfl_xor(i1[sl], m, 64);
            int   oj2 = __shfl_xor(i2[sl], m, 64);
            bool take = (oa1 < b1[sl]) || (oa1 == b1[sl] && oj1 < i1[sl]);
            float w1  = take ? oa1 : b1[sl];  int ni1 = take ? oj1 : i1[sl];
            float l1v = take ? b1[sl] : oa1;  int il1 = take ? i1[sl] : oj1;
            float wt2 = take ? oa2 : b2[sl];  int iw2 = take ? oj2 : i2[sl];
            float wt3 = take ? oa3 : b3[sl];
            float lt2v = take ? b2[sl] : oa2;
            bool t2 = wt2 < l1v;
            float nb2 = t2 ? wt2 : l1v;       int ni2 = t2 ? iw2 : il1;
            float nb3 = fminf(fmaxf(l1v, wt2), fminf(wt3, lt2v));
            b1[sl] = w1;  i1[sl] = ni1;
            b2[sl] = nb2; i2[sl] = ni2;
            b3[sl] = nb3;
        }
    }
    if (n_lo == 0) {
        #pragma unroll
        for (int reg = 0; reg < 4; ++reg) {
            int row = w * 16 + q * 4 + reg;
            rowb1[row] = b1[reg];
            rowb2[row] = b2[reg];
            rowb3[row] = b3[reg];
            rowi1[row] = i1[reg];
            rowi2[row] = i2[reg];
        }
    }
    __syncthreads();

    // ---- flag rows (wave 0): pair (b2 within margin) / full (b3 within margin) ----
    if (t < 64) {
        const float thr = rowb1[t] + MARGIN;
        const bool pf = rowb2[t] < thr;
        const bool ff = rowb3[t] < thr;      // ff implies pf (b3 >= b2)
        unsigned long long pm = __ballot(pf);
        if (t == 0) flcs = __popcll(pm);
        if (pf) {
            const int rank = __popcll(pm & ((1ULL << t) - 1ULL));
            flrows[rank] = t | (ff ? 256 : 0);
            rowfi[t] = rank;
        }
        unsigned long long fm = __ballot(ff);
        if (t == 0) nfulls = __popcll(fm);
        if (ff) {
            const int rank = __popcll(fm & ((1ULL << t) - 1ULL));
            frows2[rank] = t;
        }
    }
    __syncthreads();
    const int flc = flcs;                // block-uniform
    const int nfull = nfulls;

    if (flc > 0) {
        // stage z rows: 4 threads/row, 16 dims each (L2/L3-hot scattered reads)
        {
            const int fi = t >> 2, d0 = (t & 3) * 16;
            if (fi < flc) {
                const int r = flrows[fi] & 255;
                const float* zp = z + (size_t)b * 65536 + (size_t)d0 * 1024 + (sb + r);
                #pragma unroll
                for (int k = 0; k < 16; ++k)
                    zs[fi * 64 + d0 + k] = zp[(size_t)k * 1024];
            }
        }
        __syncthreads();
        // zn per flagged row: fl32(fp64 sequential ||z||^2) (R2-proven chain)
        if (t < flc) {
            const float* zp = zs + t * 64;
            double a = 0.0;
            for (int k = 0; k < 64; ++k) { const double v = (double)zp[k]; a = fma(v, v, a); }
            znsh[t] = (float)a;
        }
        __syncthreads();

        // ---- pair-rescue: thread per flagged (non-full) row; exact chain on {i1,i2} ----
        if (t < flc) {
            const int ent = flrows[t];
            if (!(ent & 256)) {
                const int r = ent & 255;
                const float zn = znsh[t];
                const int c1 = rowi1[r], c2 = rowi2[r];
                const float* zp = zs + t * 64;
                const float4* e1p = (const float4*)(emb + (size_t)c1 * 64);
                const float4* e2p = (const float4*)(emb + (size_t)c2 * 64);
                float m1 = 0.f, m2 = 0.f;
                #pragma unroll
                for (int k4 = 0; k4 < 16; ++k4) {    // strict sequential k (R2-exact)
                    const float4 zz = *(const float4*)(zp + k4 * 4);
                    const float4 ea = e1p[k4], eb = e2p[k4];
                    m1 = fmaf(zz.x, ea.x, m1); m1 = fmaf(zz.y, ea.y, m1);
                    m1 = fmaf(zz.z, ea.z, m1); m1 = fmaf(zz.w, ea.w, m1);
                    m2 = fmaf(zz.x, eb.x, m2); m2 = fmaf(zz.y, eb.y, m2);
                    m2 = fmaf(zz.z, eb.z, m2); m2 = fmaf(zz.w, eb.w, m2);
                }
                const float t1 = zn + e2s[c1];
                const float t2v = zn + e2s[c2];
                const float d1 = t1 - 2.0f * m1;
                const float d2 = t2v - 2.0f * m2;
                // lex-min (d, c): first-occurrence semantics
                const int cw = (d2 < d1 || (d2 == d1 && c2 < c1)) ? c2 : c1;
                rowi1[r] = cw;
            }
        }

        // ---- full-rescue: one wave per b3-flagged row (rare); lane owns 16 codes ----
        for (int fj = w; fj < nfull; fj += 4) {
            const int r = frows2[fj];
            const int fi = rowfi[r];
            const float zn = znsh[fi];
            const float4* zz4 = (const float4*)(zs + fi * 64);
            unsigned long long best = ~0ULL;
            #pragma unroll 1
            for (int j = 0; j < 16; ++j) {
                const int c = j * 64 + lane;
                const float4* ep4 = (const float4*)(emb + (size_t)c * 64);
                float m = 0.f;
                #pragma unroll
                for (int k4 = 0; k4 < 16; ++k4) {    // strict sequential k (R2-exact)
                    const float4 e4v = ep4[k4];
                    const float4 zz = zz4[k4];
                    m = fmaf(zz.x, e4v.x, m); m = fmaf(zz.y, e4v.y, m);
                    m = fmaf(zz.z, e4v.z, m); m = fmaf(zz.w, e4v.w, m);
                }
                const float tt = zn + e2s[c];
                const float d = tt - 2.0f * m;
                const unsigned long long kk = packkey(d, c);
                if (kk < best) best = kk;
            }
            #pragma unroll
            for (int mo = 32; mo > 0; mo >>= 1) {
                unsigned long long o = __shfl_xor(best, mo, 64);
                if (o < best) best = o;
            }
            if (lane == 0) rowi1[r] = (int)(unsigned)(best & 0xffffffffu);
        }
        __syncthreads();
    }

    // ---- index + hist with FINAL codes ----
    if (t < 64) {
        const int code = rowi1[t];
        out[NELEM + n0 + t] = (float)code;
        atomicAdd(&hist[code], 1u);      // distributed addresses
    }

    // ---- epilogue: COALESCED z_q_st + loss for ALL rows with final codes ----
    // (R2-validated mapping: thread (w,lane): row=lane, dims [w*16, w*16+16))
    {
        const int r = lane;
        const int code2 = rowi1[r];
        const int scol = sb + r;
        double lsum = 0.0;
        #pragma unroll
        for (int i = 0; i < 4; ++i) {
            const int d4 = w * 4 + i;
            float4 e4 = *(const float4*)(emb + code2 * 64 + d4 * 4);  // gather, L1/L2-hot
            float es[4] = {e4.x, e4.y, e4.z, e4.w};
            #pragma unroll
            for (int j = 0; j < 4; ++j) {
                int d = d4 * 4 + j;
                size_t off = (size_t)b * 65536 + (size_t)d * 1024 + scol;
                float zv = z[off];                 // coalesced 256B
                out[off] = zv + (es[j] - zv);      // coalesced 256B
                double df = (double)es[j] - (double)zv;
                lsum = fma(df, df, lsum);
            }
        }
        #pragma unroll
        for (int off = 32; off > 0; off >>= 1)
            lsum += __shfl_down(lsum, off, 64);
        if (lane == 0) wls[w] = lsum;
    }
    __syncthreads();
    if (t == 0) lossp[bk] = wls[0] + wls[1] + wls[2] + wls[3];   // NO atomic
}

// ---------------- finalize: sum loss partials + entropy ----------------
__global__ void vq_finalize_kernel(const unsigned* __restrict__ hist,
                                   const double* __restrict__ lossp,
                                   float* __restrict__ out) {
    __shared__ double red[256], red2[256];
    int t = threadIdx.x;
    double ssum = 0.0, lsum = 0.0;
    for (int i = t; i < VOCAB; i += 256) {
        double p = (double)hist[i] / (double)NROWS;
        ssum += p * log(p + 1e-10);
    }
    for (int i = t; i < 1024; i += 256) lsum += lossp[i];
    red[t] = ssum; red2[t] = lsum;
    __syncthreads();
    for (int off = 128; off > 0; off >>= 1) {
        if (t < off) { red[t] += red[t + off]; red2[t] += red2[t + off]; }
        __syncthreads();
    }
    if (t == 0) {
        double qv = red2[0] / (double)NELEM;
        out[NELEM + NROWS + 0] = (float)qv;
        out[NELEM + NROWS + 1] = (float)(qv * 0.25);
        out[NELEM + NROWS + 2] = (float)exp(-red[0]);
    }
}

extern "C" void kernel_launch(void* const* d_in, const int* in_sizes, int n_in,
                              void* d_out, int out_size, void* d_ws, size_t ws_size,
                              hipStream_t stream) {
    const float* z   = (const float*)d_in[0];   // (64,64,32,32) fp32
    const float* emb = (const float*)d_in[1];   // (1024,64) fp32
    float* out = (float*)d_out;

    float*    e2f   = (float*)d_ws;
    unsigned* hist  = (unsigned*)((char*)d_ws + 4096);
    uint4*    FB    = (uint4*)((char*)d_ws + 8192);
    double*   lossp = (double*)((char*)d_ws + 139264);

    vq_prep<<<dim3(8), dim3(256), 0, stream>>>(emb, e2f, FB, hist);
    vq_main<<<dim3(1024), dim3(256), 0, stream>>>(z, emb, e2f, FB, out, lossp, hist);
    vq_finalize_kernel<<<dim3(1), dim3(256), 0, stream>>>(hist, lossp, out);
}